// Round 1
// baseline (167.762 us; speedup 1.0000x reference)
//
#include <hip/hip_runtime.h>

// Tucker scoring: out[n] = sum_{p,q,r} U[i_n,p] V[j_n,q] W[k_n,r] G[p,q,r]
// P=Q=R=32. Strategy: precompute H[k][p][q] = sum_r G[p,q,r] W[k,r] for the
// 5000 distinct k values (20.5 MB in d_ws), then out[n] = u^T H_{k_n} v.
// 15x FLOP reduction vs fused per-sample contraction; H gathers served by L2/L3.

#define TUCKER_P 32   // == Q == R

// ---------------------------------------------------------------------------
// Kernel 1: H[k][pq] = sum_r G[pq][r] * W[k][r]
// One block of 256 threads handles 8 k values. Thread t owns pq quad t (pq =
// 4t..4t+3). G rows are reused across the 8 k's; W loads are block-uniform
// (scalar loads). ~0.33 GFLOP total.
// ---------------------------------------------------------------------------
__global__ __launch_bounds__(256) void build_H(const float* __restrict__ G,
                                               const float* __restrict__ W,
                                               float* __restrict__ H,
                                               int num_time) {
    const int pq4 = threadIdx.x;            // 0..255 -> pq in [4*pq4, 4*pq4+4)
    const int kbase = blockIdx.x * 8;

    float acc[8][4];
#pragma unroll
    for (int kk = 0; kk < 8; ++kk)
#pragma unroll
        for (int i = 0; i < 4; ++i) acc[kk][i] = 0.f;

#pragma unroll
    for (int r4 = 0; r4 < 8; ++r4) {
        float4 g[4];
#pragma unroll
        for (int i = 0; i < 4; ++i)
            g[i] = *(const float4*)(G + (size_t)(pq4 * 4 + i) * 32 + r4 * 4);
#pragma unroll
        for (int kk = 0; kk < 8; ++kk) {
            int k = kbase + kk;
            int kc = (k < num_time) ? k : (num_time - 1);  // clamp OOB loads
            float4 w = *(const float4*)(W + (size_t)kc * 32 + r4 * 4);
#pragma unroll
            for (int i = 0; i < 4; ++i) {
                acc[kk][i] += g[i].x * w.x + g[i].y * w.y + g[i].z * w.z + g[i].w * w.w;
            }
        }
    }

#pragma unroll
    for (int kk = 0; kk < 8; ++kk) {
        int k = kbase + kk;
        if (k < num_time) {
            float4 o = make_float4(acc[kk][0], acc[kk][1], acc[kk][2], acc[kk][3]);
            *(float4*)(H + (size_t)k * 1024 + pq4 * 4) = o;
        }
    }
}

// ---------------------------------------------------------------------------
// Kernel 2: one wave (64 lanes) per sample. Lane = pg*8 + qq.
//   acc4[qq] over p: 4 iterations, each a fully-coalesced 1KB float4 load of
//   the H row (index = lane + 64*it), times broadcast u[p].
//   Butterfly-reduce over pg (lane bits 3..5), dot with v quad, butterfly over
//   qq (lane bits 0..2), lane 0 stores.
// ---------------------------------------------------------------------------
__global__ __launch_bounds__(256) void tucker_eval(const int* __restrict__ I,
                                                   const int* __restrict__ J,
                                                   const int* __restrict__ K,
                                                   const float* __restrict__ U,
                                                   const float* __restrict__ V,
                                                   const float* __restrict__ H,
                                                   float* __restrict__ out,
                                                   int n_samples) {
    const int wave = (int)((blockIdx.x * (unsigned)blockDim.x + threadIdx.x) >> 6);
    const int lane = threadIdx.x & 63;
    if (wave >= n_samples) return;

    const int i = I[wave];
    const int j = J[wave];
    const int k = K[wave];

    const int qq = lane & 7;
    const int pg = lane >> 3;

    const float4* __restrict__ Hrow = (const float4*)(H + (size_t)k * 1024);
    const float* __restrict__ Urow = U + (size_t)i * 32;

    float4 acc = make_float4(0.f, 0.f, 0.f, 0.f);
#pragma unroll
    for (int it = 0; it < 4; ++it) {
        const int p = pg + it * 8;
        float4 h = Hrow[lane + it * 64];   // == (p*32 + qq*4)/4
        float up = Urow[p];
        acc.x += up * h.x;
        acc.y += up * h.y;
        acc.z += up * h.z;
        acc.w += up * h.w;
    }

    // reduce over pg (8 lanes apart)
#pragma unroll
    for (int off = 8; off < 64; off <<= 1) {
        acc.x += __shfl_xor(acc.x, off, 64);
        acc.y += __shfl_xor(acc.y, off, 64);
        acc.z += __shfl_xor(acc.z, off, 64);
        acc.w += __shfl_xor(acc.w, off, 64);
    }

    float4 v4 = ((const float4*)(V + (size_t)j * 32))[qq];
    float s = acc.x * v4.x + acc.y * v4.y + acc.z * v4.z + acc.w * v4.w;

    // reduce over qq
    s += __shfl_xor(s, 1, 64);
    s += __shfl_xor(s, 2, 64);
    s += __shfl_xor(s, 4, 64);

    if (lane == 0) out[wave] = s;
}

// ---------------------------------------------------------------------------
// Fallback (only if ws_size can't hold H): direct per-sample contraction with
// G streamed through LDS in 16KB chunks (4 p-planes at a time). Thread-per-
// sample; all threads read identical (broadcast) LDS addresses. Correctness-
// first path, ~2-4x slower than the H-table path.
// ---------------------------------------------------------------------------
__global__ __launch_bounds__(256) void tucker_direct(const int* __restrict__ I,
                                                     const int* __restrict__ J,
                                                     const int* __restrict__ K,
                                                     const float* __restrict__ U,
                                                     const float* __restrict__ V,
                                                     const float* __restrict__ W,
                                                     const float* __restrict__ G,
                                                     float* __restrict__ out,
                                                     int n_samples) {
    __shared__ float Gc[4 * 32 * 32];  // 16 KB: 4 p-planes
    const int n = blockIdx.x * blockDim.x + threadIdx.x;
    const bool active = (n < n_samples);

    int i = 0, j = 0, k = 0;
    if (active) { i = I[n]; j = J[n]; k = K[n]; }

    float4 w4[8];
#pragma unroll
    for (int r4 = 0; r4 < 8; ++r4)
        w4[r4] = ((const float4*)(W + (size_t)k * 32))[r4];

    float v[32];
#pragma unroll
    for (int q4 = 0; q4 < 8; ++q4) {
        float4 t = ((const float4*)(V + (size_t)j * 32))[q4];
        v[q4 * 4 + 0] = t.x; v[q4 * 4 + 1] = t.y;
        v[q4 * 4 + 2] = t.z; v[q4 * 4 + 3] = t.w;
    }

    const float* __restrict__ Urow = U + (size_t)i * 32;
    float acc = 0.f;

    for (int c = 0; c < 8; ++c) {
        __syncthreads();
        // cooperative load of 4096 floats (4 p-planes), coalesced float4
#pragma unroll
        for (int t = 0; t < 4; ++t) {
            int idx = threadIdx.x + t * 256;  // float4 index in [0,1024)
            ((float4*)Gc)[idx] = ((const float4*)(G + (size_t)c * 4096))[idx];
        }
        __syncthreads();

        for (int pp = 0; pp < 4; ++pp) {
            float up = Urow[c * 4 + pp];
#pragma unroll
            for (int q = 0; q < 32; ++q) {
                float t0 = 0.f;
#pragma unroll
                for (int r4 = 0; r4 < 8; ++r4) {
                    float4 g = ((const float4*)Gc)[pp * 256 + q * 8 + r4];
                    t0 += g.x * w4[r4].x + g.y * w4[r4].y + g.z * w4[r4].z + g.w * w4[r4].w;
                }
                acc += up * v[q] * t0;
            }
        }
    }

    if (active) out[n] = acc;
}

extern "C" void kernel_launch(void* const* d_in, const int* in_sizes, int n_in,
                              void* d_out, int out_size, void* d_ws, size_t ws_size,
                              hipStream_t stream) {
    const int*   I = (const int*)d_in[0];
    const int*   J = (const int*)d_in[1];
    const int*   K = (const int*)d_in[2];
    const float* U = (const float*)d_in[3];   // [NUM_USER, 32]
    const float* V = (const float*)d_in[4];   // [NUM_ITEM, 32]
    const float* W = (const float*)d_in[5];   // [NUM_TIME, 32]
    const float* G = (const float*)d_in[6];   // [32, 32, 32]
    float* out = (float*)d_out;

    const int n_samples = in_sizes[0];
    const int num_time = in_sizes[5] / 32;

    const size_t need = (size_t)num_time * 1024 * sizeof(float);

    if (ws_size >= need) {
        float* H = (float*)d_ws;
        const int blocks1 = (num_time + 7) / 8;
        build_H<<<blocks1, 256, 0, stream>>>(G, W, H, num_time);

        const long long total_threads = (long long)n_samples * 64;
        const int blocks2 = (int)((total_threads + 255) / 256);
        tucker_eval<<<blocks2, 256, 0, stream>>>(I, J, K, U, V, H, out, n_samples);
    } else {
        const int blocks = (n_samples + 255) / 256;
        tucker_direct<<<blocks, 256, 0, stream>>>(I, J, K, U, V, W, G, out, n_samples);
    }
}